// Round 7
// baseline (1326.217 us; speedup 1.0000x reference)
//
#include <hip/hip_runtime.h>
#include <hip/hip_bf16.h>
#include <cstddef>

#define N_TOK 8192
#define DIM   1024
#define HG    2048
#define NE    8
#define HEXP  4096

#define BM 128
#define BN 128
#define BK 16

typedef __attribute__((ext_vector_type(8))) short bf16x8;
typedef __attribute__((ext_vector_type(4))) float f32x4;

__device__ __forceinline__ float silu_f(float z) {
    return z / (1.0f + expf(-z));
}

// fp32 -> bf16 RNE (no NaN handling needed; inputs are finite)
__device__ __forceinline__ unsigned short f2bf(float v) {
    unsigned u = __float_as_uint(v);
    unsigned r = (u + 0x7FFFu + ((u >> 16) & 1u)) >> 16;
    return (unsigned short)r;
}

// ---------------- prep kernels ----------------

__global__ __launch_bounds__(256) void conv_x(const float* __restrict__ src,
                                              unsigned short* __restrict__ dst)
{
    const size_t total = (size_t)N_TOK * DIM;
    size_t i = ((size_t)blockIdx.x * 256 + threadIdx.x) * 4;
    const size_t step = (size_t)gridDim.x * 256 * 4;
    for (; i + 3 < total; i += step) {
        float4 v = *(const float4*)(src + i);
        ushort4 o;
        o.x = f2bf(v.x); o.y = f2bf(v.y); o.z = f2bf(v.z); o.w = f2bf(v.w);
        *(ushort4*)(dst + i) = o;
    }
}

// src f32 [R][C] -> dst bf16 [C][R], batched over blockIdx.z
__global__ __launch_bounds__(256) void transpose_conv(const float* __restrict__ src,
                                                      unsigned short* __restrict__ dst,
                                                      int R, int C)
{
    __shared__ float tile[64][65];
    const size_t bofs = (size_t)blockIdx.z * R * C;
    const float* s = src + bofs;
    unsigned short* d = dst + bofs;
    const int r0 = blockIdx.y * 64, c0 = blockIdx.x * 64;
    const int t = threadIdx.x;
    #pragma unroll
    for (int i = 0; i < 16; i++) {
        int id = t + i * 256;
        int r = id >> 6, c = id & 63;
        tile[r][c] = s[(size_t)(r0 + r) * C + c0 + c];
    }
    __syncthreads();
    #pragma unroll
    for (int i = 0; i < 16; i++) {
        int id = t + i * 256;
        int c = id >> 6, r = id & 63;
        d[(size_t)(c0 + c) * R + r0 + r] = f2bf(tile[r][c]);
    }
}

// ---------------- fp32 gate path ----------------

// C[M,Nc] = silu(A[M,K] @ B[K,Nc] + bias[Nc]) fp32, for the gate MLP layer 1
__global__ __launch_bounds__(256) void gemm_bias_silu(
    const float* __restrict__ A, const float* __restrict__ B,
    const float* __restrict__ bias, float* __restrict__ C,
    int M, int Nc, int K)
{
    __shared__ float As[BK][BM];
    __shared__ float Bs[BK][BN];

    const int tid = threadIdx.x;
    const int tx = tid & 15;
    const int ty = tid >> 4;
    const int row0 = blockIdx.y * BM;
    const int col0 = blockIdx.x * BN;

    const int ar = tid >> 2;
    const int ac = (tid & 3) << 2;
    const int br = tid >> 5;
    const int bc = (tid & 31) << 2;

    const float* Ap = A + (size_t)(row0 + ar) * K + ac;
    const float* Bp = B + (size_t)br * Nc + col0 + bc;

    float acc[8][8];
    #pragma unroll
    for (int i = 0; i < 8; i++)
        #pragma unroll
        for (int j = 0; j < 8; j++) acc[i][j] = 0.0f;

    for (int k0 = 0; k0 < K; k0 += BK) {
        float4 a0 = *(const float4*)(Ap + k0);
        float4 a1 = *(const float4*)(Ap + k0 + (size_t)64 * K);
        float4 b0 = *(const float4*)(Bp + (size_t)k0 * Nc);
        float4 b1 = *(const float4*)(Bp + (size_t)(k0 + 8) * Nc);

        __syncthreads();
        As[ac + 0][ar] = a0.x; As[ac + 1][ar] = a0.y;
        As[ac + 2][ar] = a0.z; As[ac + 3][ar] = a0.w;
        As[ac + 0][ar + 64] = a1.x; As[ac + 1][ar + 64] = a1.y;
        As[ac + 2][ar + 64] = a1.z; As[ac + 3][ar + 64] = a1.w;
        *(float4*)&Bs[br][bc]     = b0;
        *(float4*)&Bs[br + 8][bc] = b1;
        __syncthreads();

        #pragma unroll
        for (int k = 0; k < BK; k++) {
            float a[8], b[8];
            *(float4*)&a[0] = *(const float4*)&As[k][ty * 8];
            *(float4*)&a[4] = *(const float4*)&As[k][ty * 8 + 4];
            *(float4*)&b[0] = *(const float4*)&Bs[k][tx * 8];
            *(float4*)&b[4] = *(const float4*)&Bs[k][tx * 8 + 4];
            #pragma unroll
            for (int i = 0; i < 8; i++)
                #pragma unroll
                for (int j = 0; j < 8; j++)
                    acc[i][j] = fmaf(a[i], b[j], acc[i][j]);
        }
    }

    #pragma unroll
    for (int i = 0; i < 8; i++) {
        const int row = row0 + ty * 8 + i;
        const int col = col0 + tx * 8;
        float4 o0, o1;
        o0.x = silu_f(acc[i][0] + bias[col + 0]);
        o0.y = silu_f(acc[i][1] + bias[col + 1]);
        o0.z = silu_f(acc[i][2] + bias[col + 2]);
        o0.w = silu_f(acc[i][3] + bias[col + 3]);
        o1.x = silu_f(acc[i][4] + bias[col + 4]);
        o1.y = silu_f(acc[i][5] + bias[col + 5]);
        o1.z = silu_f(acc[i][6] + bias[col + 6]);
        o1.w = silu_f(acc[i][7] + bias[col + 7]);
        *(float4*)&C[(size_t)row * Nc + col]     = o0;
        *(float4*)&C[(size_t)row * Nc + col + 4] = o1;
    }
}

// gates = g1 @ Wg2 + bg2 ; top2 + softmax ; scatter to per-expert buckets
__global__ __launch_bounds__(256) void gate2_topk(
    const float* __restrict__ g1, const float* __restrict__ Wg2,
    const float* __restrict__ bg2,
    unsigned* __restrict__ tok_list, float* __restrict__ w_list,
    unsigned* __restrict__ counts)
{
    const int wid  = threadIdx.x >> 6;
    const int lane = threadIdx.x & 63;
    const int t = blockIdx.x * 4 + wid;
    if (t >= N_TOK) return;

    float acc[NE];
    #pragma unroll
    for (int e = 0; e < NE; e++) acc[e] = 0.0f;

    const float* g = g1 + (size_t)t * HG;
    for (int k = lane; k < HG; k += 64) {
        const float gv = g[k];
        const float4 wa = *(const float4*)(Wg2 + (size_t)k * NE);
        const float4 wb = *(const float4*)(Wg2 + (size_t)k * NE + 4);
        acc[0] = fmaf(gv, wa.x, acc[0]);
        acc[1] = fmaf(gv, wa.y, acc[1]);
        acc[2] = fmaf(gv, wa.z, acc[2]);
        acc[3] = fmaf(gv, wa.w, acc[3]);
        acc[4] = fmaf(gv, wb.x, acc[4]);
        acc[5] = fmaf(gv, wb.y, acc[5]);
        acc[6] = fmaf(gv, wb.z, acc[6]);
        acc[7] = fmaf(gv, wb.w, acc[7]);
    }
    #pragma unroll
    for (int off = 32; off > 0; off >>= 1) {
        #pragma unroll
        for (int e = 0; e < NE; e++)
            acc[e] += __shfl_down(acc[e], off);
    }
    if (lane == 0) {
        float v0 = -3.4e38f, v1 = -3.4e38f;
        int i0 = 0, i1 = 0;
        #pragma unroll
        for (int e = 0; e < NE; e++) {
            const float v = acc[e] + bg2[e];
            if (v > v0) { v1 = v0; i1 = i0; v0 = v; i0 = e; }
            else if (v > v1) { v1 = v; i1 = e; }
        }
        const float e1 = expf(v1 - v0);
        const float inv = 1.0f / (1.0f + e1);
        const unsigned p0 = atomicAdd(&counts[i0], 1u);
        tok_list[i0 * N_TOK + p0] = (unsigned)t;
        w_list [i0 * N_TOK + p0] = inv;
        const unsigned p1 = atomicAdd(&counts[i1], 1u);
        tok_list[i1 * N_TOK + p1] = (unsigned)t;
        w_list [i1 * N_TOK + p1] = e1 * inv;
    }
}

// meta[0..7] = counts (in), meta[16] = n_tiles (out)
__global__ void build_tiles(unsigned* __restrict__ meta,
                            unsigned* __restrict__ tile_e,
                            unsigned* __restrict__ tile_rs,
                            unsigned* __restrict__ tile_re)
{
    if (threadIdx.x == 0 && blockIdx.x == 0) {
        int nt = 0;
        for (int e = 0; e < NE; e++) {
            const unsigned c = meta[e];
            for (unsigned s = 0; s < c; s += 128) {
                tile_e[nt]  = (unsigned)e;
                tile_rs[nt] = (unsigned)(e * N_TOK) + s;
                unsigned re = s + 128; if (re > c) re = c;
                tile_re[nt] = (unsigned)(e * N_TOK) + re;
                nt++;
            }
        }
        meta[16] = (unsigned)nt;
    }
}

// ---------------- bf16 MFMA GEMMs ----------------
// Fragment layouts (gfx950 mfma_f32_16x16x32_bf16, guide-verified):
//   A: lane l holds A[l&15][(l>>4)*8 + j], j=0..7
//   B: lane l holds B[(l>>4)*8 + j][l&15]
//   C/D: lane l reg r -> row=(l>>4)*4+r, col=l&15   [m89/m91]
// LDS tiles stored [row][K=64] bf16 (128B rows) with XOR swizzle
// byte ^= ((row&7)<<4) for conflict-free ds_read_b128.

#define TBK 64

// H[8192][4096] bf16 = silu(Xb[8192][1024] @ W1t^T + b1); W1t is [4096][1024] (N,K)
__global__ __launch_bounds__(256) void ff1_mfma(
    const unsigned short* __restrict__ Xb,
    const unsigned short* __restrict__ W1t,
    const float* __restrict__ b1,
    unsigned short* __restrict__ H)
{
    __shared__ __align__(16) unsigned short As[128][TBK];
    __shared__ __align__(16) unsigned short Bs[128][TBK];

    const int tid  = threadIdx.x;
    const int wave = tid >> 6;
    const int lane = tid & 63;
    const int wm = wave >> 1, wn = wave & 1;
    const int l15 = lane & 15;
    const int lk  = lane >> 4;
    const int row0 = blockIdx.y * 128;
    const int col0 = blockIdx.x * 128;

    f32x4 acc[4][4] = {};

    for (int k0 = 0; k0 < DIM; k0 += TBK) {
        __syncthreads();
        #pragma unroll
        for (int it = 0; it < 4; it++) {
            const int id = tid + it * 256;
            const int r = id >> 3, cb = id & 7;
            const int sb = (cb * 16) ^ ((r & 7) << 4);
            uint4 va = *(const uint4*)(Xb  + (size_t)(row0 + r) * DIM + k0 + cb * 8);
            uint4 vb = *(const uint4*)(W1t + (size_t)(col0 + r) * DIM + k0 + cb * 8);
            *(uint4*)((char*)&As[r][0] + sb) = va;
            *(uint4*)((char*)&Bs[r][0] + sb) = vb;
        }
        __syncthreads();

        #pragma unroll
        for (int ks = 0; ks < 2; ks++) {
            bf16x8 af[4], bfr[4];
            const int kb = (ks * 32 + lk * 8) * 2;
            #pragma unroll
            for (int mi = 0; mi < 4; mi++) {
                const int r = wm * 64 + mi * 16 + l15;
                af[mi] = *(const bf16x8*)((const char*)&As[r][0] + (kb ^ ((r & 7) << 4)));
            }
            #pragma unroll
            for (int ni = 0; ni < 4; ni++) {
                const int r = wn * 64 + ni * 16 + l15;
                bfr[ni] = *(const bf16x8*)((const char*)&Bs[r][0] + (kb ^ ((r & 7) << 4)));
            }
            #pragma unroll
            for (int mi = 0; mi < 4; mi++)
                #pragma unroll
                for (int ni = 0; ni < 4; ni++)
                    acc[mi][ni] = __builtin_amdgcn_mfma_f32_16x16x32_bf16(
                        af[mi], bfr[ni], acc[mi][ni], 0, 0, 0);
        }
    }

    #pragma unroll
    for (int ni = 0; ni < 4; ni++) {
        const int gc = col0 + wn * 64 + ni * 16 + l15;
        const float bv = b1[gc];
        #pragma unroll
        for (int mi = 0; mi < 4; mi++) {
            #pragma unroll
            for (int r = 0; r < 4; r++) {
                const int gr = row0 + wm * 64 + mi * 16 + lk * 4 + r;
                H[(size_t)gr * HEXP + gc] = f2bf(silu_f(acc[mi][ni][r] + bv));
            }
        }
    }
}

// grouped ff2: out[tok] += w * (h[tok] @ W2t[e]^T + b2[e]); W2t is [e][1024][4096] (N,K)
__global__ __launch_bounds__(256) void ff2_mfma(
    const unsigned short* __restrict__ Hb,
    const unsigned short* __restrict__ W2t,
    const float* __restrict__ b2,
    const unsigned* __restrict__ tok_list, const float* __restrict__ w_list,
    const unsigned* __restrict__ meta,
    const unsigned* __restrict__ tile_e, const unsigned* __restrict__ tile_rs,
    const unsigned* __restrict__ tile_re,
    float* __restrict__ out)
{
    const unsigned nt = meta[16];
    if (blockIdx.x >= nt) return;

    const int e  = (int)tile_e[blockIdx.x];
    const int rs = (int)tile_rs[blockIdx.x];
    const int re = (int)tile_re[blockIdx.x];
    const int col0 = blockIdx.y * 128;

    __shared__ __align__(16) unsigned short As[128][TBK];
    __shared__ __align__(16) unsigned short Bs[128][TBK];
    __shared__ unsigned tokr[128];

    const int tid  = threadIdx.x;
    const int wave = tid >> 6;
    const int lane = tid & 63;
    const int wm = wave >> 1, wn = wave & 1;
    const int l15 = lane & 15;
    const int lk  = lane >> 4;

    if (tid < 128)
        tokr[tid] = (rs + tid < re) ? tok_list[rs + tid] : tok_list[rs];

    const unsigned short* Bsrc = W2t + (size_t)e * DIM * HEXP;

    f32x4 acc[4][4] = {};

    for (int k0 = 0; k0 < HEXP; k0 += TBK) {
        __syncthreads();   // also publishes tokr on first iteration
        #pragma unroll
        for (int it = 0; it < 4; it++) {
            const int id = tid + it * 256;
            const int r = id >> 3, cb = id & 7;
            const int sb = (cb * 16) ^ ((r & 7) << 4);
            uint4 va = *(const uint4*)(Hb + (size_t)tokr[r] * HEXP + k0 + cb * 8);
            uint4 vb = *(const uint4*)(Bsrc + (size_t)(col0 + r) * HEXP + k0 + cb * 8);
            *(uint4*)((char*)&As[r][0] + sb) = va;
            *(uint4*)((char*)&Bs[r][0] + sb) = vb;
        }
        __syncthreads();

        #pragma unroll
        for (int ks = 0; ks < 2; ks++) {
            bf16x8 af[4], bfr[4];
            const int kb = (ks * 32 + lk * 8) * 2;
            #pragma unroll
            for (int mi = 0; mi < 4; mi++) {
                const int r = wm * 64 + mi * 16 + l15;
                af[mi] = *(const bf16x8*)((const char*)&As[r][0] + (kb ^ ((r & 7) << 4)));
            }
            #pragma unroll
            for (int ni = 0; ni < 4; ni++) {
                const int r = wn * 64 + ni * 16 + l15;
                bfr[ni] = *(const bf16x8*)((const char*)&Bs[r][0] + (kb ^ ((r & 7) << 4)));
            }
            #pragma unroll
            for (int mi = 0; mi < 4; mi++)
                #pragma unroll
                for (int ni = 0; ni < 4; ni++)
                    acc[mi][ni] = __builtin_amdgcn_mfma_f32_16x16x32_bf16(
                        af[mi], bfr[ni], acc[mi][ni], 0, 0, 0);
        }
    }

    #pragma unroll
    for (int ni = 0; ni < 4; ni++) {
        const int gc = col0 + wn * 64 + ni * 16 + l15;
        const float bv = b2[(size_t)e * DIM + gc];
        #pragma unroll
        for (int mi = 0; mi < 4; mi++) {
            #pragma unroll
            for (int r = 0; r < 4; r++) {
                const int lr = wm * 64 + mi * 16 + lk * 4 + r;
                if (rs + lr < re) {
                    const unsigned tok = tokr[lr];
                    const float w = w_list[rs + lr];
                    atomicAdd(out + (size_t)tok * DIM + gc, w * (acc[mi][ni][r] + bv));
                }
            }
        }
    }
}

extern "C" void kernel_launch(void* const* d_in, const int* in_sizes, int n_in,
                              void* d_out, int out_size, void* d_ws, size_t ws_size,
                              hipStream_t stream)
{
    const float* x   = (const float*)d_in[0];
    const float* Wg1 = (const float*)d_in[1];
    const float* bg1 = (const float*)d_in[2];
    const float* Wg2 = (const float*)d_in[3];
    const float* bg2 = (const float*)d_in[4];
    const float* W1  = (const float*)d_in[5];
    const float* b1  = (const float*)d_in[6];
    const float* W2  = (const float*)d_in[7];
    const float* b2  = (const float*)d_in[8];
    float* out = (float*)d_out;

    char* ws = (char*)d_ws;
    const size_t MB = 1024 * 1024;
    unsigned short* xb   = (unsigned short*)(ws);             // 16MB: [8192][1024] bf16
    unsigned short* W1t  = (unsigned short*)(ws + 16 * MB);   //  8MB: [4096][1024] bf16
    unsigned short* hbuf = (unsigned short*)(ws + 24 * MB);   // 64MB: [8192][4096] bf16
    float*          g1   = (float*)        (ws + 88 * MB);    // 64MB fp32, later reused:
    unsigned short* W2t  = (unsigned short*)(ws + 88 * MB);   // 64MB: [8][1024][4096] bf16
    unsigned* tok_list = (unsigned*)(ws + 152 * MB);          // [8][8192] u32
    float*    w_list   = (float*)   (ws + 152 * MB + 65536 * 4);
    unsigned* meta     = (unsigned*)(ws + 152 * MB + 65536 * 8);
    unsigned* tile_e   = meta + 1024;
    unsigned* tile_rs  = meta + 1280;
    unsigned* tile_re  = meta + 1536;

    (void)hipMemsetAsync(d_out, 0, (size_t)out_size * sizeof(float), stream);
    (void)hipMemsetAsync(meta, 0, 128, stream);

    const dim3 blk(256);
    // prep: x -> bf16 ; W1 [1024][4096] -> W1t [4096][1024] bf16
    conv_x<<<dim3(2048), blk, 0, stream>>>(x, xb);
    transpose_conv<<<dim3(HEXP / 64, DIM / 64, 1), blk, 0, stream>>>(W1, W1t, DIM, HEXP);
    // gate (fp32): g1 = silu(x @ Wg1 + bg1) ; top2 softmax scatter
    gemm_bias_silu<<<dim3(HG / BN, N_TOK / BM), blk, 0, stream>>>(
        x, Wg1, bg1, g1, N_TOK, HG, DIM);
    gate2_topk<<<dim3(N_TOK / 4), blk, 0, stream>>>(
        g1, Wg2, bg2, tok_list, w_list, meta);
    build_tiles<<<dim3(1), dim3(64), 0, stream>>>(meta, tile_e, tile_rs, tile_re);
    // ff1 (bf16 MFMA): h = silu(x @ W1 + b1) -> bf16
    ff1_mfma<<<dim3(HEXP / 128, N_TOK / 128), blk, 0, stream>>>(xb, W1t, b1, hbuf);
    // W2 [8][4096][1024] -> W2t [8][1024][4096] bf16 (overwrites dead g1)
    transpose_conv<<<dim3(DIM / 64, HEXP / 64, NE), blk, 0, stream>>>(W2, W2t, HEXP, DIM);
    // ff2 (bf16 MFMA, grouped, weighted atomic combine)
    ff2_mfma<<<dim3(N_TOK * 2 / 128 + NE, DIM / 128), blk, 0, stream>>>(
        hbuf, W2t, b2, tok_list, w_list, meta, tile_e, tile_rs, tile_re, out);
}

// Round 8
// 1129.012 us; speedup vs baseline: 1.1747x; 1.1747x over previous
//
#include <hip/hip_runtime.h>
#include <hip/hip_bf16.h>
#include <cstddef>

#define N_TOK 8192
#define DIM   1024
#define HG    2048
#define NE    8
#define HEXP  4096

#define BM 128
#define BN 128
#define BK 16
#define THETA 0.05f

typedef __attribute__((ext_vector_type(8))) short bf16x8;
typedef __attribute__((ext_vector_type(4))) float f32x4;

__device__ __forceinline__ float silu_f(float z) {
    return z / (1.0f + expf(-z));
}

__device__ __forceinline__ unsigned short f2bf(float v) {
    unsigned u = __float_as_uint(v);
    unsigned r = (u + 0x7FFFu + ((u >> 16) & 1u)) >> 16;
    return (unsigned short)r;
}

__device__ __forceinline__ float bf2f(unsigned short v) {
    return __uint_as_float((unsigned)v << 16);
}

// ---------------- prep kernels ----------------

__global__ __launch_bounds__(256) void conv_x(const float* __restrict__ src,
                                              unsigned short* __restrict__ dst)
{
    const size_t total = (size_t)N_TOK * DIM;
    size_t i = ((size_t)blockIdx.x * 256 + threadIdx.x) * 4;
    const size_t step = (size_t)gridDim.x * 256 * 4;
    for (; i + 3 < total; i += step) {
        float4 v = *(const float4*)(src + i);
        ushort4 o;
        o.x = f2bf(v.x); o.y = f2bf(v.y); o.z = f2bf(v.z); o.w = f2bf(v.w);
        *(ushort4*)(dst + i) = o;
    }
}

// src f32 [R][C] -> dst bf16 [C][R], batched over blockIdx.z
__global__ __launch_bounds__(256) void transpose_conv(const float* __restrict__ src,
                                                      unsigned short* __restrict__ dst,
                                                      int R, int C)
{
    __shared__ float tile[64][65];
    const size_t bofs = (size_t)blockIdx.z * R * C;
    const float* s = src + bofs;
    unsigned short* d = dst + bofs;
    const int r0 = blockIdx.y * 64, c0 = blockIdx.x * 64;
    const int t = threadIdx.x;
    #pragma unroll
    for (int i = 0; i < 16; i++) {
        int id = t + i * 256;
        int r = id >> 6, c = id & 63;
        tile[r][c] = s[(size_t)(r0 + r) * C + c0 + c];
    }
    __syncthreads();
    #pragma unroll
    for (int i = 0; i < 16; i++) {
        int id = t + i * 256;
        int c = id >> 6, r = id & 63;
        d[(size_t)(c0 + c) * R + r0 + r] = f2bf(tile[r][c]);
    }
}

// ---------------- bf16 MFMA GEMM (gate1 + ff1) ----------------
// C[8192][Nc] bf16 = silu(A[8192][1024] @ Bt^T + bias); Bt is [Nc][1024] (N,K) bf16
// LDS [row][64] bf16, 128B rows, XOR swizzle byte ^= ((row&7)<<4).

#define TBK 64

__global__ __launch_bounds__(256) void gemm_bf16_silu(
    const unsigned short* __restrict__ A,
    const unsigned short* __restrict__ Bt,
    const float* __restrict__ bias,
    unsigned short* __restrict__ C,
    int Nc)
{
    __shared__ __align__(16) unsigned short As[128][TBK];
    __shared__ __align__(16) unsigned short Bs[128][TBK];

    const int tid  = threadIdx.x;
    const int wave = tid >> 6;
    const int lane = tid & 63;
    const int wm = wave >> 1, wn = wave & 1;
    const int l15 = lane & 15;
    const int lk  = lane >> 4;
    const int row0 = blockIdx.y * 128;
    const int col0 = blockIdx.x * 128;

    f32x4 acc[4][4] = {};

    for (int k0 = 0; k0 < DIM; k0 += TBK) {
        __syncthreads();
        #pragma unroll
        for (int it = 0; it < 4; it++) {
            const int id = tid + it * 256;
            const int r = id >> 3, cb = id & 7;
            const int sb = (cb * 16) ^ ((r & 7) << 4);
            uint4 va = *(const uint4*)(A  + (size_t)(row0 + r) * DIM + k0 + cb * 8);
            uint4 vb = *(const uint4*)(Bt + (size_t)(col0 + r) * DIM + k0 + cb * 8);
            *(uint4*)((char*)&As[r][0] + sb) = va;
            *(uint4*)((char*)&Bs[r][0] + sb) = vb;
        }
        __syncthreads();

        #pragma unroll
        for (int ks = 0; ks < 2; ks++) {
            bf16x8 af[4], bfr[4];
            const int kb = (ks * 32 + lk * 8) * 2;
            #pragma unroll
            for (int mi = 0; mi < 4; mi++) {
                const int r = wm * 64 + mi * 16 + l15;
                af[mi] = *(const bf16x8*)((const char*)&As[r][0] + (kb ^ ((r & 7) << 4)));
            }
            #pragma unroll
            for (int ni = 0; ni < 4; ni++) {
                const int r = wn * 64 + ni * 16 + l15;
                bfr[ni] = *(const bf16x8*)((const char*)&Bs[r][0] + (kb ^ ((r & 7) << 4)));
            }
            #pragma unroll
            for (int mi = 0; mi < 4; mi++)
                #pragma unroll
                for (int ni = 0; ni < 4; ni++)
                    acc[mi][ni] = __builtin_amdgcn_mfma_f32_16x16x32_bf16(
                        af[mi], bfr[ni], acc[mi][ni], 0, 0, 0);
        }
    }

    #pragma unroll
    for (int ni = 0; ni < 4; ni++) {
        const int gc = col0 + wn * 64 + ni * 16 + l15;
        const float bv = bias[gc];
        #pragma unroll
        for (int mi = 0; mi < 4; mi++) {
            #pragma unroll
            for (int r = 0; r < 4; r++) {
                const int gr = row0 + wm * 64 + mi * 16 + lk * 4 + r;
                C[(size_t)gr * Nc + gc] = f2bf(silu_f(acc[mi][ni][r] + bv));
            }
        }
    }
}

// ---------------- gate: logits + top2/flag ----------------
// logits from bf16 g1; if rank2-rank3 margin < THETA -> flag for fp32 recompute

__global__ __launch_bounds__(256) void gate2_topk_flag(
    const unsigned short* __restrict__ g1b, const float* __restrict__ Wg2,
    const float* __restrict__ bg2,
    unsigned* __restrict__ tok_list, float* __restrict__ w_list,
    unsigned* __restrict__ meta, unsigned* __restrict__ flaglist)
{
    const int wid  = threadIdx.x >> 6;
    const int lane = threadIdx.x & 63;
    const int t = blockIdx.x * 4 + wid;
    if (t >= N_TOK) return;

    float acc[NE];
    #pragma unroll
    for (int e = 0; e < NE; e++) acc[e] = 0.0f;

    const unsigned short* g = g1b + (size_t)t * HG;
    for (int kb = lane * 8; kb < HG; kb += 512) {
        ushort4 ga = *(const ushort4*)(g + kb);
        ushort4 gb = *(const ushort4*)(g + kb + 4);
        float gv[8];
        gv[0] = bf2f(ga.x); gv[1] = bf2f(ga.y); gv[2] = bf2f(ga.z); gv[3] = bf2f(ga.w);
        gv[4] = bf2f(gb.x); gv[5] = bf2f(gb.y); gv[6] = bf2f(gb.z); gv[7] = bf2f(gb.w);
        #pragma unroll
        for (int j = 0; j < 8; j++) {
            const float4 wa = *(const float4*)(Wg2 + (size_t)(kb + j) * NE);
            const float4 wb = *(const float4*)(Wg2 + (size_t)(kb + j) * NE + 4);
            acc[0] = fmaf(gv[j], wa.x, acc[0]);
            acc[1] = fmaf(gv[j], wa.y, acc[1]);
            acc[2] = fmaf(gv[j], wa.z, acc[2]);
            acc[3] = fmaf(gv[j], wa.w, acc[3]);
            acc[4] = fmaf(gv[j], wb.x, acc[4]);
            acc[5] = fmaf(gv[j], wb.y, acc[5]);
            acc[6] = fmaf(gv[j], wb.z, acc[6]);
            acc[7] = fmaf(gv[j], wb.w, acc[7]);
        }
    }
    #pragma unroll
    for (int off = 32; off > 0; off >>= 1) {
        #pragma unroll
        for (int e = 0; e < NE; e++)
            acc[e] += __shfl_down(acc[e], off);
    }
    if (lane == 0) {
        float v0 = -3.4e38f, v1 = -3.4e38f, v2 = -3.4e38f;
        int i0 = 0, i1 = 0;
        #pragma unroll
        for (int e = 0; e < NE; e++) {
            const float v = acc[e] + bg2[e];
            if (v > v0)      { v2 = v1; v1 = v0; i1 = i0; v0 = v; i0 = e; }
            else if (v > v1) { v2 = v1; v1 = v; i1 = e; }
            else if (v > v2) { v2 = v; }
        }
        if (v1 - v2 < THETA) {
            const unsigned p = atomicAdd(&meta[17], 1u);
            flaglist[p] = (unsigned)t;
        } else {
            const float e1 = expf(v1 - v0);
            const float inv = 1.0f / (1.0f + e1);
            const unsigned p0 = atomicAdd(&meta[i0], 1u);
            tok_list[i0 * N_TOK + p0] = (unsigned)t;
            w_list [i0 * N_TOK + p0] = inv;
            const unsigned p1 = atomicAdd(&meta[i1], 1u);
            tok_list[i1 * N_TOK + p1] = (unsigned)t;
            w_list [i1 * N_TOK + p1] = e1 * inv;
        }
    }
}

// fp32 gather-GEMM over flagged tokens: g1f[f][2048] = silu(x[flag[f]] @ Wg1 + bg1)
__global__ __launch_bounds__(256) void regate_gemm(
    const float* __restrict__ x, const float* __restrict__ Wg1,
    const float* __restrict__ bg1,
    const unsigned* __restrict__ flaglist, const unsigned* __restrict__ meta,
    float* __restrict__ g1f)
{
    const int nflag = (int)meta[17];
    const int rs = blockIdx.y * BM;
    if (rs >= nflag) return;
    const int re = (rs + BM < nflag) ? rs + BM : nflag;
    const int col0 = blockIdx.x * BN;

    __shared__ float As[BK][BM];
    __shared__ float Bs[BK][BN];

    const int tid = threadIdx.x;
    const int tx = tid & 15;
    const int ty = tid >> 4;
    const int ar = tid >> 2;
    const int ac = (tid & 3) << 2;
    const int br = tid >> 5;
    const int bc = (tid & 31) << 2;

    const int r0 = rs + ar;
    const int r1 = rs + ar + 64;
    const unsigned t0 = flaglist[(r0 < re) ? r0 : rs];
    const unsigned t1 = flaglist[(r1 < re) ? r1 : rs];
    const float* A0 = x + (size_t)t0 * DIM + ac;
    const float* A1 = x + (size_t)t1 * DIM + ac;
    const float* Bp = Wg1 + (size_t)br * HG + col0 + bc;

    float acc[8][8];
    #pragma unroll
    for (int i = 0; i < 8; i++)
        #pragma unroll
        for (int j = 0; j < 8; j++) acc[i][j] = 0.0f;

    for (int k0 = 0; k0 < DIM; k0 += BK) {
        const float4 a0 = *(const float4*)(A0 + k0);
        const float4 a1 = *(const float4*)(A1 + k0);
        const float4 b0 = *(const float4*)(Bp + (size_t)k0 * HG);
        const float4 b1 = *(const float4*)(Bp + (size_t)(k0 + 8) * HG);

        __syncthreads();
        As[ac + 0][ar] = a0.x; As[ac + 1][ar] = a0.y;
        As[ac + 2][ar] = a0.z; As[ac + 3][ar] = a0.w;
        As[ac + 0][ar + 64] = a1.x; As[ac + 1][ar + 64] = a1.y;
        As[ac + 2][ar + 64] = a1.z; As[ac + 3][ar + 64] = a1.w;
        *(float4*)&Bs[br][bc]     = b0;
        *(float4*)&Bs[br + 8][bc] = b1;
        __syncthreads();

        #pragma unroll
        for (int k = 0; k < BK; k++) {
            float a[8], b[8];
            *(float4*)&a[0] = *(const float4*)&As[k][ty * 8];
            *(float4*)&a[4] = *(const float4*)&As[k][ty * 8 + 4];
            *(float4*)&b[0] = *(const float4*)&Bs[k][tx * 8];
            *(float4*)&b[4] = *(const float4*)&Bs[k][tx * 8 + 4];
            #pragma unroll
            for (int i = 0; i < 8; i++)
                #pragma unroll
                for (int j = 0; j < 8; j++)
                    acc[i][j] = fmaf(a[i], b[j], acc[i][j]);
        }
    }

    #pragma unroll
    for (int i = 0; i < 8; i++) {
        const int row = rs + ty * 8 + i;
        if (row < re) {
            const int col = col0 + tx * 8;
            #pragma unroll
            for (int j = 0; j < 8; j++)
                g1f[(size_t)row * HG + col + j] = silu_f(acc[i][j] + bg1[col + j]);
        }
    }
}

// fp32 top2 over recomputed rows; always scatter
__global__ __launch_bounds__(256) void regate_top2(
    const float* __restrict__ g1f, const float* __restrict__ Wg2,
    const float* __restrict__ bg2,
    const unsigned* __restrict__ flaglist,
    unsigned* __restrict__ tok_list, float* __restrict__ w_list,
    unsigned* __restrict__ meta)
{
    const int wid  = threadIdx.x >> 6;
    const int lane = threadIdx.x & 63;
    const int f = blockIdx.x * 4 + wid;
    const int nflag = (int)meta[17];
    if (f >= nflag) return;
    const unsigned t = flaglist[f];

    float acc[NE];
    #pragma unroll
    for (int e = 0; e < NE; e++) acc[e] = 0.0f;

    const float* g = g1f + (size_t)f * HG;
    for (int k = lane; k < HG; k += 64) {
        const float gv = g[k];
        const float4 wa = *(const float4*)(Wg2 + (size_t)k * NE);
        const float4 wb = *(const float4*)(Wg2 + (size_t)k * NE + 4);
        acc[0] = fmaf(gv, wa.x, acc[0]);
        acc[1] = fmaf(gv, wa.y, acc[1]);
        acc[2] = fmaf(gv, wa.z, acc[2]);
        acc[3] = fmaf(gv, wa.w, acc[3]);
        acc[4] = fmaf(gv, wb.x, acc[4]);
        acc[5] = fmaf(gv, wb.y, acc[5]);
        acc[6] = fmaf(gv, wb.z, acc[6]);
        acc[7] = fmaf(gv, wb.w, acc[7]);
    }
    #pragma unroll
    for (int off = 32; off > 0; off >>= 1) {
        #pragma unroll
        for (int e = 0; e < NE; e++)
            acc[e] += __shfl_down(acc[e], off);
    }
    if (lane == 0) {
        float v0 = -3.4e38f, v1 = -3.4e38f;
        int i0 = 0, i1 = 0;
        #pragma unroll
        for (int e = 0; e < NE; e++) {
            const float v = acc[e] + bg2[e];
            if (v > v0) { v1 = v0; i1 = i0; v0 = v; i0 = e; }
            else if (v > v1) { v1 = v; i1 = e; }
        }
        const float e1 = expf(v1 - v0);
        const float inv = 1.0f / (1.0f + e1);
        const unsigned p0 = atomicAdd(&meta[i0], 1u);
        tok_list[i0 * N_TOK + p0] = (unsigned)t;
        w_list [i0 * N_TOK + p0] = inv;
        const unsigned p1 = atomicAdd(&meta[i1], 1u);
        tok_list[i1 * N_TOK + p1] = (unsigned)t;
        w_list [i1 * N_TOK + p1] = e1 * inv;
    }
}

// meta[0..7] = counts (in), meta[16] = n_tiles (out)
__global__ void build_tiles(unsigned* __restrict__ meta,
                            unsigned* __restrict__ tile_e,
                            unsigned* __restrict__ tile_rs,
                            unsigned* __restrict__ tile_re)
{
    if (threadIdx.x == 0 && blockIdx.x == 0) {
        int nt = 0;
        for (int e = 0; e < NE; e++) {
            const unsigned c = meta[e];
            for (unsigned s = 0; s < c; s += 128) {
                tile_e[nt]  = (unsigned)e;
                tile_rs[nt] = (unsigned)(e * N_TOK) + s;
                unsigned re = s + 128; if (re > c) re = c;
                tile_re[nt] = (unsigned)(e * N_TOK) + re;
                nt++;
            }
        }
        meta[16] = (unsigned)nt;
    }
}

// grouped ff2: out[tok] += w * (h[tok] @ W2t[e]^T + b2[e]); W2t is [e][1024][4096] (N,K)
__global__ __launch_bounds__(256) void ff2_mfma(
    const unsigned short* __restrict__ Hb,
    const unsigned short* __restrict__ W2t,
    const float* __restrict__ b2,
    const unsigned* __restrict__ tok_list, const float* __restrict__ w_list,
    const unsigned* __restrict__ meta,
    const unsigned* __restrict__ tile_e, const unsigned* __restrict__ tile_rs,
    const unsigned* __restrict__ tile_re,
    float* __restrict__ out)
{
    const unsigned nt = meta[16];
    if (blockIdx.x >= nt) return;

    const int e  = (int)tile_e[blockIdx.x];
    const int rs = (int)tile_rs[blockIdx.x];
    const int re = (int)tile_re[blockIdx.x];
    const int col0 = blockIdx.y * 128;

    __shared__ __align__(16) unsigned short As[128][TBK];
    __shared__ __align__(16) unsigned short Bs[128][TBK];
    __shared__ unsigned tokr[128];

    const int tid  = threadIdx.x;
    const int wave = tid >> 6;
    const int lane = tid & 63;
    const int wm = wave >> 1, wn = wave & 1;
    const int l15 = lane & 15;
    const int lk  = lane >> 4;

    if (tid < 128)
        tokr[tid] = (rs + tid < re) ? tok_list[rs + tid] : tok_list[rs];

    const unsigned short* Bsrc = W2t + (size_t)e * DIM * HEXP;

    f32x4 acc[4][4] = {};

    for (int k0 = 0; k0 < HEXP; k0 += TBK) {
        __syncthreads();
        #pragma unroll
        for (int it = 0; it < 4; it++) {
            const int id = tid + it * 256;
            const int r = id >> 3, cb = id & 7;
            const int sb = (cb * 16) ^ ((r & 7) << 4);
            uint4 va = *(const uint4*)(Hb + (size_t)tokr[r] * HEXP + k0 + cb * 8);
            uint4 vb = *(const uint4*)(Bsrc + (size_t)(col0 + r) * HEXP + k0 + cb * 8);
            *(uint4*)((char*)&As[r][0] + sb) = va;
            *(uint4*)((char*)&Bs[r][0] + sb) = vb;
        }
        __syncthreads();

        #pragma unroll
        for (int ks = 0; ks < 2; ks++) {
            bf16x8 af[4], bfr[4];
            const int kb = (ks * 32 + lk * 8) * 2;
            #pragma unroll
            for (int mi = 0; mi < 4; mi++) {
                const int r = wm * 64 + mi * 16 + l15;
                af[mi] = *(const bf16x8*)((const char*)&As[r][0] + (kb ^ ((r & 7) << 4)));
            }
            #pragma unroll
            for (int ni = 0; ni < 4; ni++) {
                const int r = wn * 64 + ni * 16 + l15;
                bfr[ni] = *(const bf16x8*)((const char*)&Bs[r][0] + (kb ^ ((r & 7) << 4)));
            }
            #pragma unroll
            for (int mi = 0; mi < 4; mi++)
                #pragma unroll
                for (int ni = 0; ni < 4; ni++)
                    acc[mi][ni] = __builtin_amdgcn_mfma_f32_16x16x32_bf16(
                        af[mi], bfr[ni], acc[mi][ni], 0, 0, 0);
        }
    }

    #pragma unroll
    for (int ni = 0; ni < 4; ni++) {
        const int gc = col0 + wn * 64 + ni * 16 + l15;
        const float bv = b2[(size_t)e * DIM + gc];
        #pragma unroll
        for (int mi = 0; mi < 4; mi++) {
            #pragma unroll
            for (int r = 0; r < 4; r++) {
                const int lr = wm * 64 + mi * 16 + lk * 4 + r;
                if (rs + lr < re) {
                    const unsigned tok = tokr[lr];
                    const float w = w_list[rs + lr];
                    atomicAdd(out + (size_t)tok * DIM + gc, w * (acc[mi][ni][r] + bv));
                }
            }
        }
    }
}

extern "C" void kernel_launch(void* const* d_in, const int* in_sizes, int n_in,
                              void* d_out, int out_size, void* d_ws, size_t ws_size,
                              hipStream_t stream)
{
    const float* x   = (const float*)d_in[0];
    const float* Wg1 = (const float*)d_in[1];
    const float* bg1 = (const float*)d_in[2];
    const float* Wg2 = (const float*)d_in[3];
    const float* bg2 = (const float*)d_in[4];
    const float* W1  = (const float*)d_in[5];
    const float* b1  = (const float*)d_in[6];
    const float* W2  = (const float*)d_in[7];
    const float* b2  = (const float*)d_in[8];
    float* out = (float*)d_out;

    char* ws = (char*)d_ws;
    const size_t MB = 1024 * 1024;
    // layout (region 28..92MB time-shared: g1b -> g1f -> hbuf)
    unsigned short* xb   = (unsigned short*)(ws);             // 16MB [8192][1024] bf16
    unsigned short* W1t  = (unsigned short*)(ws + 16 * MB);   //  8MB [4096][1024] bf16
    unsigned short* Wg1t = (unsigned short*)(ws + 24 * MB);   //  4MB [2048][1024] bf16
    unsigned short* g1b  = (unsigned short*)(ws + 28 * MB);   // 32MB [8192][2048] bf16
    float*          g1f  = (float*)        (ws + 28 * MB);    // 64MB [nflag][2048] f32
    unsigned short* hbuf = (unsigned short*)(ws + 28 * MB);   // 64MB [8192][4096] bf16
    unsigned short* W2t  = (unsigned short*)(ws + 92 * MB);   // 64MB [8][1024][4096] bf16
    unsigned* tok_list = (unsigned*)(ws + 156 * MB);          // [8][8192] u32
    float*    w_list   = (float*)   (ws + 156 * MB + 65536 * 4);
    unsigned* meta     = (unsigned*)(ws + 156 * MB + 65536 * 8); // [0..7]=counts,[16]=ntiles,[17]=nflag
    unsigned* tile_e   = meta + 1024;
    unsigned* tile_rs  = meta + 1280;
    unsigned* tile_re  = meta + 1536;
    unsigned* flaglist = meta + 2048;                            // [8192] u32

    (void)hipMemsetAsync(d_out, 0, (size_t)out_size * sizeof(float), stream);
    (void)hipMemsetAsync(meta, 0, 128, stream);

    const dim3 blk(256);
    // prep
    conv_x<<<dim3(2048), blk, 0, stream>>>(x, xb);
    transpose_conv<<<dim3(HG / 64, DIM / 64, 1), blk, 0, stream>>>(Wg1, Wg1t, DIM, HG);
    // gate1 (bf16 MFMA): g1b = silu(x @ Wg1 + bg1)
    gemm_bf16_silu<<<dim3(HG / 128, N_TOK / 128), blk, 0, stream>>>(xb, Wg1t, bg1, g1b, HG);
    // logits + top2 with margin flagging
    gate2_topk_flag<<<dim3(N_TOK / 4), blk, 0, stream>>>(
        g1b, Wg2, bg2, tok_list, w_list, meta, flaglist);
    // fp32 recompute of flagged tokens (g1b dead; g1f overlays it)
    regate_gemm<<<dim3(HG / BN, N_TOK / BM), blk, 0, stream>>>(
        x, Wg1, bg1, flaglist, meta, g1f);
    regate_top2<<<dim3(N_TOK / 4), blk, 0, stream>>>(
        g1f, Wg2, bg2, flaglist, tok_list, w_list, meta);
    // tile table
    build_tiles<<<dim3(1), dim3(64), 0, stream>>>(meta, tile_e, tile_rs, tile_re);
    // ff1 (bf16 MFMA): hbuf = silu(x @ W1 + b1)  (overwrites dead g1f)
    transpose_conv<<<dim3(HEXP / 64, DIM / 64, 1), blk, 0, stream>>>(W1, W1t, DIM, HEXP);
    gemm_bf16_silu<<<dim3(HEXP / 128, N_TOK / 128), blk, 0, stream>>>(xb, W1t, b1, hbuf, HEXP);
    // W2 -> W2t bf16
    transpose_conv<<<dim3(DIM / 64, HEXP / 64, NE), blk, 0, stream>>>(W2, W2t, HEXP, DIM);
    // grouped ff2
    ff2_mfma<<<dim3(N_TOK * 2 / 128 + NE, DIM / 128), blk, 0, stream>>>(
        hbuf, W2t, b2, tok_list, w_list, meta, tile_e, tile_rs, tile_re, out);
}

// Round 9
// 1091.496 us; speedup vs baseline: 1.2150x; 1.0344x over previous
//
#include <hip/hip_runtime.h>
#include <hip/hip_bf16.h>
#include <cstddef>

#define N_TOK 8192
#define DIM   1024
#define HG    2048
#define NE    8
#define HEXP  4096

#define BM 128
#define BN 128
#define BK 16
#define THETA 0.05f

typedef __attribute__((ext_vector_type(8))) short bf16x8;
typedef __attribute__((ext_vector_type(4))) float f32x4;

__device__ __forceinline__ float silu_f(float z) {
    return z / (1.0f + expf(-z));
}

__device__ __forceinline__ unsigned short f2bf(float v) {
    unsigned u = __float_as_uint(v);
    unsigned r = (u + 0x7FFFu + ((u >> 16) & 1u)) >> 16;
    return (unsigned short)r;
}

__device__ __forceinline__ float bf2f(unsigned short v) {
    return __uint_as_float((unsigned)v << 16);
}

// async global->LDS, 16B per lane; LDS dest = wave-uniform base + lane*16
__device__ __forceinline__ void gl16(const unsigned short* g, unsigned short* l) {
    __builtin_amdgcn_global_load_lds(
        (const __attribute__((address_space(1))) unsigned int*)(const void*)g,
        (__attribute__((address_space(3))) unsigned int*)(void*)l, 16, 0, 0);
}

// ---------------- prep kernels ----------------

__global__ __launch_bounds__(256) void conv_x(const float* __restrict__ src,
                                              unsigned short* __restrict__ dst)
{
    const size_t total = (size_t)N_TOK * DIM;
    size_t i = ((size_t)blockIdx.x * 256 + threadIdx.x) * 4;
    const size_t step = (size_t)gridDim.x * 256 * 4;
    for (; i + 3 < total; i += step) {
        float4 v = *(const float4*)(src + i);
        ushort4 o;
        o.x = f2bf(v.x); o.y = f2bf(v.y); o.z = f2bf(v.z); o.w = f2bf(v.w);
        *(ushort4*)(dst + i) = o;
    }
}

// src f32 [R][C] -> dst bf16 [C][R], batched over blockIdx.z
__global__ __launch_bounds__(256) void transpose_conv(const float* __restrict__ src,
                                                      unsigned short* __restrict__ dst,
                                                      int R, int C)
{
    __shared__ float tile[64][65];
    const size_t bofs = (size_t)blockIdx.z * R * C;
    const float* s = src + bofs;
    unsigned short* d = dst + bofs;
    const int r0 = blockIdx.y * 64, c0 = blockIdx.x * 64;
    const int t = threadIdx.x;
    #pragma unroll
    for (int i = 0; i < 16; i++) {
        int id = t + i * 256;
        int r = id >> 6, c = id & 63;
        tile[r][c] = s[(size_t)(r0 + r) * C + c0 + c];
    }
    __syncthreads();
    #pragma unroll
    for (int i = 0; i < 16; i++) {
        int id = t + i * 256;
        int c = id >> 6, r = id & 63;
        d[(size_t)(c0 + c) * R + r0 + r] = f2bf(tile[r][c]);
    }
}

// ---------------- bf16 MFMA GEMM (gate1 + ff1) ----------------
// C[8192][Nc] bf16 = silu(A[8192][1024] @ Bt^T + bias); Bt is [Nc][1024] (N,K) bf16
// LDS [row][64] bf16 (128B rows). Staging: global_load_lds w16, linear LDS dest,
// pre-swizzled global source (cb_src = (lane&7)^(lane>>3)); read applies the same
// XOR (byte ^= (row&7)<<4)  -> conflict-free ds_read_b128 (T21 both-sides rule).

#define TBK 64

__global__ __launch_bounds__(256) void gemm_bf16_silu(
    const unsigned short* __restrict__ A,
    const unsigned short* __restrict__ Bt,
    const float* __restrict__ bias,
    unsigned short* __restrict__ C,
    int Nc)
{
    __shared__ __align__(16) unsigned short As[128][TBK];
    __shared__ __align__(16) unsigned short Bs[128][TBK];

    const int tid  = threadIdx.x;
    const int wave = tid >> 6;
    const int lane = tid & 63;
    const int wm = wave >> 1, wn = wave & 1;
    const int l15 = lane & 15;
    const int lk  = lane >> 4;
    const int row0 = blockIdx.y * 128;
    const int col0 = blockIdx.x * 128;

    // staging addresses: wave w stages rows w*32 .. w*32+31 (4 issues x 8 rows)
    const int l8  = lane >> 3;            // row within an 8-row issue
    const int cbs = (lane & 7) ^ l8;      // pre-swizzled source 16B-block
    const unsigned short* pA[4];
    const unsigned short* pB[4];
    #pragma unroll
    for (int i = 0; i < 4; i++) {
        const int r = wave * 32 + i * 8 + l8;
        pA[i] = A  + (size_t)(row0 + r) * DIM + cbs * 8;
        pB[i] = Bt + (size_t)(col0 + r) * DIM + cbs * 8;
    }

    f32x4 acc[4][4] = {};

    for (int k0 = 0; k0 < DIM; k0 += TBK) {
        __syncthreads();
        #pragma unroll
        for (int i = 0; i < 4; i++) {
            gl16(pA[i] + k0, &As[wave * 32 + i * 8][0]);
            gl16(pB[i] + k0, &Bs[wave * 32 + i * 8][0]);
        }
        __syncthreads();   // drains vmcnt -> tile resident

        #pragma unroll
        for (int ks = 0; ks < 2; ks++) {
            bf16x8 af[4], bfr[4];
            const int kb = (ks * 32 + lk * 8) * 2;
            #pragma unroll
            for (int mi = 0; mi < 4; mi++) {
                const int r = wm * 64 + mi * 16 + l15;
                af[mi] = *(const bf16x8*)((const char*)&As[r][0] + (kb ^ ((r & 7) << 4)));
            }
            #pragma unroll
            for (int ni = 0; ni < 4; ni++) {
                const int r = wn * 64 + ni * 16 + l15;
                bfr[ni] = *(const bf16x8*)((const char*)&Bs[r][0] + (kb ^ ((r & 7) << 4)));
            }
            #pragma unroll
            for (int mi = 0; mi < 4; mi++)
                #pragma unroll
                for (int ni = 0; ni < 4; ni++)
                    acc[mi][ni] = __builtin_amdgcn_mfma_f32_16x16x32_bf16(
                        af[mi], bfr[ni], acc[mi][ni], 0, 0, 0);
        }
    }

    #pragma unroll
    for (int ni = 0; ni < 4; ni++) {
        const int gc = col0 + wn * 64 + ni * 16 + l15;
        const float bv = bias[gc];
        #pragma unroll
        for (int mi = 0; mi < 4; mi++) {
            #pragma unroll
            for (int r = 0; r < 4; r++) {
                const int gr = row0 + wm * 64 + mi * 16 + lk * 4 + r;
                C[(size_t)gr * Nc + gc] = f2bf(silu_f(acc[mi][ni][r] + bv));
            }
        }
    }
}

// ---------------- gate: logits + top2/flag ----------------

__global__ __launch_bounds__(256) void gate2_topk_flag(
    const unsigned short* __restrict__ g1b, const float* __restrict__ Wg2,
    const float* __restrict__ bg2,
    unsigned* __restrict__ tok_list, float* __restrict__ w_list,
    unsigned* __restrict__ meta, unsigned* __restrict__ flaglist)
{
    const int wid  = threadIdx.x >> 6;
    const int lane = threadIdx.x & 63;
    const int t = blockIdx.x * 4 + wid;
    if (t >= N_TOK) return;

    float acc[NE];
    #pragma unroll
    for (int e = 0; e < NE; e++) acc[e] = 0.0f;

    const unsigned short* g = g1b + (size_t)t * HG;
    for (int kb = lane * 8; kb < HG; kb += 512) {
        ushort4 ga = *(const ushort4*)(g + kb);
        ushort4 gb = *(const ushort4*)(g + kb + 4);
        float gv[8];
        gv[0] = bf2f(ga.x); gv[1] = bf2f(ga.y); gv[2] = bf2f(ga.z); gv[3] = bf2f(ga.w);
        gv[4] = bf2f(gb.x); gv[5] = bf2f(gb.y); gv[6] = bf2f(gb.z); gv[7] = bf2f(gb.w);
        #pragma unroll
        for (int j = 0; j < 8; j++) {
            const float4 wa = *(const float4*)(Wg2 + (size_t)(kb + j) * NE);
            const float4 wb = *(const float4*)(Wg2 + (size_t)(kb + j) * NE + 4);
            acc[0] = fmaf(gv[j], wa.x, acc[0]);
            acc[1] = fmaf(gv[j], wa.y, acc[1]);
            acc[2] = fmaf(gv[j], wa.z, acc[2]);
            acc[3] = fmaf(gv[j], wa.w, acc[3]);
            acc[4] = fmaf(gv[j], wb.x, acc[4]);
            acc[5] = fmaf(gv[j], wb.y, acc[5]);
            acc[6] = fmaf(gv[j], wb.z, acc[6]);
            acc[7] = fmaf(gv[j], wb.w, acc[7]);
        }
    }
    #pragma unroll
    for (int off = 32; off > 0; off >>= 1) {
        #pragma unroll
        for (int e = 0; e < NE; e++)
            acc[e] += __shfl_down(acc[e], off);
    }
    if (lane == 0) {
        float v0 = -3.4e38f, v1 = -3.4e38f, v2 = -3.4e38f;
        int i0 = 0, i1 = 0;
        #pragma unroll
        for (int e = 0; e < NE; e++) {
            const float v = acc[e] + bg2[e];
            if (v > v0)      { v2 = v1; v1 = v0; i1 = i0; v0 = v; i0 = e; }
            else if (v > v1) { v2 = v1; v1 = v; i1 = e; }
            else if (v > v2) { v2 = v; }
        }
        if (v1 - v2 < THETA) {
            const unsigned p = atomicAdd(&meta[17], 1u);
            flaglist[p] = (unsigned)t;
        } else {
            const float e1 = expf(v1 - v0);
            const float inv = 1.0f / (1.0f + e1);
            const unsigned p0 = atomicAdd(&meta[i0], 1u);
            tok_list[i0 * N_TOK + p0] = (unsigned)t;
            w_list [i0 * N_TOK + p0] = inv;
            const unsigned p1 = atomicAdd(&meta[i1], 1u);
            tok_list[i1 * N_TOK + p1] = (unsigned)t;
            w_list [i1 * N_TOK + p1] = e1 * inv;
        }
    }
}

// fp32 gather-GEMM over flagged tokens: g1f[f][2048] = silu(x[flag[f]] @ Wg1 + bg1)
__global__ __launch_bounds__(256) void regate_gemm(
    const float* __restrict__ x, const float* __restrict__ Wg1,
    const float* __restrict__ bg1,
    const unsigned* __restrict__ flaglist, const unsigned* __restrict__ meta,
    float* __restrict__ g1f)
{
    const int nflag = (int)meta[17];
    const int rs = blockIdx.y * BM;
    if (rs >= nflag) return;
    const int re = (rs + BM < nflag) ? rs + BM : nflag;
    const int col0 = blockIdx.x * BN;

    __shared__ float As[BK][BM];
    __shared__ float Bs[BK][BN];

    const int tid = threadIdx.x;
    const int tx = tid & 15;
    const int ty = tid >> 4;
    const int ar = tid >> 2;
    const int ac = (tid & 3) << 2;
    const int br = tid >> 5;
    const int bc = (tid & 31) << 2;

    const int r0 = rs + ar;
    const int r1 = rs + ar + 64;
    const unsigned t0 = flaglist[(r0 < re) ? r0 : rs];
    const unsigned t1 = flaglist[(r1 < re) ? r1 : rs];
    const float* A0 = x + (size_t)t0 * DIM + ac;
    const float* A1 = x + (size_t)t1 * DIM + ac;
    const float* Bp = Wg1 + (size_t)br * HG + col0 + bc;

    float acc[8][8];
    #pragma unroll
    for (int i = 0; i < 8; i++)
        #pragma unroll
        for (int j = 0; j < 8; j++) acc[i][j] = 0.0f;

    for (int k0 = 0; k0 < DIM; k0 += BK) {
        const float4 a0 = *(const float4*)(A0 + k0);
        const float4 a1 = *(const float4*)(A1 + k0);
        const float4 b0 = *(const float4*)(Bp + (size_t)k0 * HG);
        const float4 b1 = *(const float4*)(Bp + (size_t)(k0 + 8) * HG);

        __syncthreads();
        As[ac + 0][ar] = a0.x; As[ac + 1][ar] = a0.y;
        As[ac + 2][ar] = a0.z; As[ac + 3][ar] = a0.w;
        As[ac + 0][ar + 64] = a1.x; As[ac + 1][ar + 64] = a1.y;
        As[ac + 2][ar + 64] = a1.z; As[ac + 3][ar + 64] = a1.w;
        *(float4*)&Bs[br][bc]     = b0;
        *(float4*)&Bs[br + 8][bc] = b1;
        __syncthreads();

        #pragma unroll
        for (int k = 0; k < BK; k++) {
            float a[8], b[8];
            *(float4*)&a[0] = *(const float4*)&As[k][ty * 8];
            *(float4*)&a[4] = *(const float4*)&As[k][ty * 8 + 4];
            *(float4*)&b[0] = *(const float4*)&Bs[k][tx * 8];
            *(float4*)&b[4] = *(const float4*)&Bs[k][tx * 8 + 4];
            #pragma unroll
            for (int i = 0; i < 8; i++)
                #pragma unroll
                for (int j = 0; j < 8; j++)
                    acc[i][j] = fmaf(a[i], b[j], acc[i][j]);
        }
    }

    #pragma unroll
    for (int i = 0; i < 8; i++) {
        const int row = rs + ty * 8 + i;
        if (row < re) {
            const int col = col0 + tx * 8;
            #pragma unroll
            for (int j = 0; j < 8; j++)
                g1f[(size_t)row * HG + col + j] = silu_f(acc[i][j] + bg1[col + j]);
        }
    }
}

// fp32 top2 over recomputed rows; always scatter
__global__ __launch_bounds__(256) void regate_top2(
    const float* __restrict__ g1f, const float* __restrict__ Wg2,
    const float* __restrict__ bg2,
    const unsigned* __restrict__ flaglist,
    unsigned* __restrict__ tok_list, float* __restrict__ w_list,
    unsigned* __restrict__ meta)
{
    const int wid  = threadIdx.x >> 6;
    const int lane = threadIdx.x & 63;
    const int f = blockIdx.x * 4 + wid;
    const int nflag = (int)meta[17];
    if (f >= nflag) return;
    const unsigned t = flaglist[f];

    float acc[NE];
    #pragma unroll
    for (int e = 0; e < NE; e++) acc[e] = 0.0f;

    const float* g = g1f + (size_t)f * HG;
    for (int k = lane; k < HG; k += 64) {
        const float gv = g[k];
        const float4 wa = *(const float4*)(Wg2 + (size_t)k * NE);
        const float4 wb = *(const float4*)(Wg2 + (size_t)k * NE + 4);
        acc[0] = fmaf(gv, wa.x, acc[0]);
        acc[1] = fmaf(gv, wa.y, acc[1]);
        acc[2] = fmaf(gv, wa.z, acc[2]);
        acc[3] = fmaf(gv, wa.w, acc[3]);
        acc[4] = fmaf(gv, wb.x, acc[4]);
        acc[5] = fmaf(gv, wb.y, acc[5]);
        acc[6] = fmaf(gv, wb.z, acc[6]);
        acc[7] = fmaf(gv, wb.w, acc[7]);
    }
    #pragma unroll
    for (int off = 32; off > 0; off >>= 1) {
        #pragma unroll
        for (int e = 0; e < NE; e++)
            acc[e] += __shfl_down(acc[e], off);
    }
    if (lane == 0) {
        float v0 = -3.4e38f, v1 = -3.4e38f;
        int i0 = 0, i1 = 0;
        #pragma unroll
        for (int e = 0; e < NE; e++) {
            const float v = acc[e] + bg2[e];
            if (v > v0) { v1 = v0; i1 = i0; v0 = v; i0 = e; }
            else if (v > v1) { v1 = v; i1 = e; }
        }
        const float e1 = expf(v1 - v0);
        const float inv = 1.0f / (1.0f + e1);
        const unsigned p0 = atomicAdd(&meta[i0], 1u);
        tok_list[i0 * N_TOK + p0] = (unsigned)t;
        w_list [i0 * N_TOK + p0] = inv;
        const unsigned p1 = atomicAdd(&meta[i1], 1u);
        tok_list[i1 * N_TOK + p1] = (unsigned)t;
        w_list [i1 * N_TOK + p1] = e1 * inv;
    }
}

// meta[0..7] = counts (in), meta[16] = n_tiles (out)
__global__ void build_tiles(unsigned* __restrict__ meta,
                            unsigned* __restrict__ tile_e,
                            unsigned* __restrict__ tile_rs,
                            unsigned* __restrict__ tile_re)
{
    if (threadIdx.x == 0 && blockIdx.x == 0) {
        int nt = 0;
        for (int e = 0; e < NE; e++) {
            const unsigned c = meta[e];
            for (unsigned s = 0; s < c; s += 128) {
                tile_e[nt]  = (unsigned)e;
                tile_rs[nt] = (unsigned)(e * N_TOK) + s;
                unsigned re = s + 128; if (re > c) re = c;
                tile_re[nt] = (unsigned)(e * N_TOK) + re;
                nt++;
            }
        }
        meta[16] = (unsigned)nt;
    }
}

// grouped ff2: out[tok] += w * (h[tok] @ W2t[e]^T + b2[e]); W2t is [e][1024][4096] (N,K)
__global__ __launch_bounds__(256) void ff2_mfma(
    const unsigned short* __restrict__ Hb,
    const unsigned short* __restrict__ W2t,
    const float* __restrict__ b2,
    const unsigned* __restrict__ tok_list, const float* __restrict__ w_list,
    const unsigned* __restrict__ meta,
    const unsigned* __restrict__ tile_e, const unsigned* __restrict__ tile_rs,
    const unsigned* __restrict__ tile_re,
    float* __restrict__ out)
{
    const unsigned nt = meta[16];
    if (blockIdx.x >= nt) return;

    const int e  = (int)tile_e[blockIdx.x];
    const int rs = (int)tile_rs[blockIdx.x];
    const int re = (int)tile_re[blockIdx.x];
    const int col0 = blockIdx.y * 128;

    __shared__ __align__(16) unsigned short As[128][TBK];
    __shared__ __align__(16) unsigned short Bs[128][TBK];
    __shared__ unsigned tokr[128];

    const int tid  = threadIdx.x;
    const int wave = tid >> 6;
    const int lane = tid & 63;
    const int wm = wave >> 1, wn = wave & 1;
    const int l15 = lane & 15;
    const int lk  = lane >> 4;

    if (tid < 128)
        tokr[tid] = (rs + tid < re) ? tok_list[rs + tid] : tok_list[rs];
    __syncthreads();

    const unsigned short* Bsrc = W2t + (size_t)e * DIM * HEXP;

    // staging addresses (wave w stages rows w*32..w*32+31)
    const int l8  = lane >> 3;
    const int cbs = (lane & 7) ^ l8;
    const unsigned short* pA[4];
    const unsigned short* pB[4];
    #pragma unroll
    for (int i = 0; i < 4; i++) {
        const int r = wave * 32 + i * 8 + l8;
        pA[i] = Hb + (size_t)tokr[r] * HEXP + cbs * 8;
        pB[i] = Bsrc + (size_t)(col0 + r) * HEXP + cbs * 8;
    }

    f32x4 acc[4][4] = {};

    for (int k0 = 0; k0 < HEXP; k0 += TBK) {
        __syncthreads();
        #pragma unroll
        for (int i = 0; i < 4; i++) {
            gl16(pA[i] + k0, &As[wave * 32 + i * 8][0]);
            gl16(pB[i] + k0, &Bs[wave * 32 + i * 8][0]);
        }
        __syncthreads();

        #pragma unroll
        for (int ks = 0; ks < 2; ks++) {
            bf16x8 af[4], bfr[4];
            const int kb = (ks * 32 + lk * 8) * 2;
            #pragma unroll
            for (int mi = 0; mi < 4; mi++) {
                const int r = wm * 64 + mi * 16 + l15;
                af[mi] = *(const bf16x8*)((const char*)&As[r][0] + (kb ^ ((r & 7) << 4)));
            }
            #pragma unroll
            for (int ni = 0; ni < 4; ni++) {
                const int r = wn * 64 + ni * 16 + l15;
                bfr[ni] = *(const bf16x8*)((const char*)&Bs[r][0] + (kb ^ ((r & 7) << 4)));
            }
            #pragma unroll
            for (int mi = 0; mi < 4; mi++)
                #pragma unroll
                for (int ni = 0; ni < 4; ni++)
                    acc[mi][ni] = __builtin_amdgcn_mfma_f32_16x16x32_bf16(
                        af[mi], bfr[ni], acc[mi][ni], 0, 0, 0);
        }
    }

    #pragma unroll
    for (int ni = 0; ni < 4; ni++) {
        const int gc = col0 + wn * 64 + ni * 16 + l15;
        const float bv = b2[(size_t)e * DIM + gc];
        #pragma unroll
        for (int mi = 0; mi < 4; mi++) {
            #pragma unroll
            for (int r = 0; r < 4; r++) {
                const int lr = wm * 64 + mi * 16 + lk * 4 + r;
                if (rs + lr < re) {
                    const unsigned tok = tokr[lr];
                    const float w = w_list[rs + lr];
                    atomicAdd(out + (size_t)tok * DIM + gc, w * (acc[mi][ni][r] + bv));
                }
            }
        }
    }
}

extern "C" void kernel_launch(void* const* d_in, const int* in_sizes, int n_in,
                              void* d_out, int out_size, void* d_ws, size_t ws_size,
                              hipStream_t stream)
{
    const float* x   = (const float*)d_in[0];
    const float* Wg1 = (const float*)d_in[1];
    const float* bg1 = (const float*)d_in[2];
    const float* Wg2 = (const float*)d_in[3];
    const float* bg2 = (const float*)d_in[4];
    const float* W1  = (const float*)d_in[5];
    const float* b1  = (const float*)d_in[6];
    const float* W2  = (const float*)d_in[7];
    const float* b2  = (const float*)d_in[8];
    float* out = (float*)d_out;

    char* ws = (char*)d_ws;
    const size_t MB = 1024 * 1024;
    // layout (region 28..92MB time-shared: g1b -> g1f -> hbuf)
    unsigned short* xb   = (unsigned short*)(ws);             // 16MB [8192][1024] bf16
    unsigned short* W1t  = (unsigned short*)(ws + 16 * MB);   //  8MB [4096][1024] bf16
    unsigned short* Wg1t = (unsigned short*)(ws + 24 * MB);   //  4MB [2048][1024] bf16
    unsigned short* g1b  = (unsigned short*)(ws + 28 * MB);   // 32MB [8192][2048] bf16
    float*          g1f  = (float*)        (ws + 28 * MB);    // 64MB [nflag][2048] f32
    unsigned short* hbuf = (unsigned short*)(ws + 28 * MB);   // 64MB [8192][4096] bf16
    unsigned short* W2t  = (unsigned short*)(ws + 92 * MB);   // 64MB [8][1024][4096] bf16
    unsigned* tok_list = (unsigned*)(ws + 156 * MB);          // [8][8192] u32
    float*    w_list   = (float*)   (ws + 156 * MB + 65536 * 4);
    unsigned* meta     = (unsigned*)(ws + 156 * MB + 65536 * 8); // [0..7]=counts,[16]=ntiles,[17]=nflag
    unsigned* tile_e   = meta + 1024;
    unsigned* tile_rs  = meta + 1280;
    unsigned* tile_re  = meta + 1536;
    unsigned* flaglist = meta + 2048;                            // [8192] u32

    (void)hipMemsetAsync(d_out, 0, (size_t)out_size * sizeof(float), stream);
    (void)hipMemsetAsync(meta, 0, 128, stream);

    const dim3 blk(256);
    // prep
    conv_x<<<dim3(2048), blk, 0, stream>>>(x, xb);
    transpose_conv<<<dim3(HG / 64, DIM / 64, 1), blk, 0, stream>>>(Wg1, Wg1t, DIM, HG);
    // gate1 (bf16 MFMA): g1b = silu(x @ Wg1 + bg1)
    gemm_bf16_silu<<<dim3(HG / 128, N_TOK / 128), blk, 0, stream>>>(xb, Wg1t, bg1, g1b, HG);
    // logits + top2 with margin flagging
    gate2_topk_flag<<<dim3(N_TOK / 4), blk, 0, stream>>>(
        g1b, Wg2, bg2, tok_list, w_list, meta, flaglist);
    // fp32 recompute of flagged tokens (g1b dead; g1f overlays it)
    regate_gemm<<<dim3(HG / BN, N_TOK / BM), blk, 0, stream>>>(
        x, Wg1, bg1, flaglist, meta, g1f);
    regate_top2<<<dim3(N_TOK / 4), blk, 0, stream>>>(
        g1f, Wg2, bg2, flaglist, tok_list, w_list, meta);
    // tile table
    build_tiles<<<dim3(1), dim3(64), 0, stream>>>(meta, tile_e, tile_rs, tile_re);
    // ff1 (bf16 MFMA): hbuf = silu(x @ W1 + b1)  (overwrites dead g1f)
    transpose_conv<<<dim3(HEXP / 64, DIM / 64, 1), blk, 0, stream>>>(W1, W1t, DIM, HEXP);
    gemm_bf16_silu<<<dim3(HEXP / 128, N_TOK / 128), blk, 0, stream>>>(xb, W1t, b1, hbuf, HEXP);
    // W2 -> W2t bf16
    transpose_conv<<<dim3(DIM / 64, HEXP / 64, NE), blk, 0, stream>>>(W2, W2t, HEXP, DIM);
    // grouped ff2
    ff2_mfma<<<dim3(N_TOK * 2 / 128 + NE, DIM / 128), blk, 0, stream>>>(
        hbuf, W2t, b2, tok_list, w_list, meta, tile_e, tile_rs, tile_re, out);
}

// Round 11
// 1072.057 us; speedup vs baseline: 1.2371x; 1.0181x over previous
//
#include <hip/hip_runtime.h>
#include <hip/hip_bf16.h>
#include <cstddef>

#define N_TOK 8192
#define DIM   1024
#define HG    2048
#define NE    8
#define HEXP  4096

#define BM 128
#define BN 128
#define BK 16
#define THETA 0.05f

typedef __attribute__((ext_vector_type(8))) short bf16x8;
typedef __attribute__((ext_vector_type(4))) float f32x4;

__device__ __forceinline__ float silu_f(float z) {
    return z / (1.0f + expf(-z));
}

__device__ __forceinline__ unsigned short f2bf(float v) {
    unsigned u = __float_as_uint(v);
    unsigned r = (u + 0x7FFFu + ((u >> 16) & 1u)) >> 16;
    return (unsigned short)r;
}

__device__ __forceinline__ float bf2f(unsigned short v) {
    return __uint_as_float((unsigned)v << 16);
}

// async global->LDS, 16B per lane; LDS dest = wave-uniform base + lane*16
__device__ __forceinline__ void gl16(const unsigned short* g, unsigned short* l) {
    __builtin_amdgcn_global_load_lds(
        (const __attribute__((address_space(1))) unsigned int*)(const void*)g,
        (__attribute__((address_space(3))) unsigned int*)(void*)l, 16, 0, 0);
}

// ---------------- prep kernels ----------------

__global__ __launch_bounds__(256) void conv_x(const float* __restrict__ src,
                                              unsigned short* __restrict__ dst)
{
    const size_t total = (size_t)N_TOK * DIM;
    size_t i = ((size_t)blockIdx.x * 256 + threadIdx.x) * 4;
    const size_t step = (size_t)gridDim.x * 256 * 4;
    for (; i + 3 < total; i += step) {
        float4 v = *(const float4*)(src + i);
        ushort4 o;
        o.x = f2bf(v.x); o.y = f2bf(v.y); o.z = f2bf(v.z); o.w = f2bf(v.w);
        *(ushort4*)(dst + i) = o;
    }
}

// src f32 [R][C] -> dst bf16 [C][R], batched over blockIdx.z
__global__ __launch_bounds__(256) void transpose_conv(const float* __restrict__ src,
                                                      unsigned short* __restrict__ dst,
                                                      int R, int C)
{
    __shared__ float tile[64][65];
    const size_t bofs = (size_t)blockIdx.z * R * C;
    const float* s = src + bofs;
    unsigned short* d = dst + bofs;
    const int r0 = blockIdx.y * 64, c0 = blockIdx.x * 64;
    const int t = threadIdx.x;
    #pragma unroll
    for (int i = 0; i < 16; i++) {
        int id = t + i * 256;
        int r = id >> 6, c = id & 63;
        tile[r][c] = s[(size_t)(r0 + r) * C + c0 + c];
    }
    __syncthreads();
    #pragma unroll
    for (int i = 0; i < 16; i++) {
        int id = t + i * 256;
        int c = id >> 6, r = id & 63;
        d[(size_t)(c0 + c) * R + r0 + r] = f2bf(tile[r][c]);
    }
}

// ---------------- bf16 MFMA GEMM template bits ----------------
// BK=32, double-buffered LDS with 1-step prefetch (T3 minimum-2-phase):
//   STAGE(next) issued BEFORE compute(cur); one __syncthreads per step
//   (its implicit vmcnt(0) drain overlaps compute).
// LDS rows 64B (32 bf16). Staging: gl16 linear dest (lane*16B: row=l>>2,
// chunk=l&3), source chunk pre-swizzled (l&3)^((l>>3)&3); read applies
// byte ^= ((r>>1)&3)<<4  -> residual 2-way aliasing (free, m136).

#define TBK 32

// C[8192][Nc] bf16 = silu(A[8192][1024] @ Bt^T + bias); Bt is [Nc][1024] (N,K)
__global__ __launch_bounds__(256) void gemm_bf16_silu(
    const unsigned short* __restrict__ A,
    const unsigned short* __restrict__ Bt,
    const float* __restrict__ bias,
    unsigned short* __restrict__ C,
    int Nc)
{
    __shared__ __align__(16) unsigned short As[2][128][TBK];
    __shared__ __align__(16) unsigned short Bs[2][128][TBK];

    const int tid  = threadIdx.x;
    const int wave = tid >> 6;
    const int lane = tid & 63;
    const int wm = wave >> 1, wn = wave & 1;
    const int l15 = lane & 15;
    const int lk  = lane >> 4;
    const int row0 = blockIdx.y * 128;
    const int col0 = blockIdx.x * 128;

    // staging: wave w stages rows w*32..w*32+31 of A and B (2 issues each)
    const int srow = lane >> 2;                       // 0..15 within issue
    const int cbs  = (lane & 3) ^ ((lane >> 3) & 3);  // pre-swizzled src chunk
    const unsigned short* pA[2];
    const unsigned short* pB[2];
    #pragma unroll
    for (int i = 0; i < 2; i++) {
        const int r = wave * 32 + i * 16 + srow;
        pA[i] = A  + (size_t)(row0 + r) * DIM + cbs * 8;
        pB[i] = Bt + (size_t)(col0 + r) * DIM + cbs * 8;
    }

    f32x4 acc[4][4] = {};

    // prologue: stage k0=0 into buf0
    #pragma unroll
    for (int i = 0; i < 2; i++) {
        gl16(pA[i], &As[0][wave * 32 + i * 16][0]);
        gl16(pB[i], &Bs[0][wave * 32 + i * 16][0]);
    }
    __syncthreads();

    int db = 0;
    for (int k0 = 0; k0 < DIM; k0 += TBK) {
        if (k0 + TBK < DIM) {
            #pragma unroll
            for (int i = 0; i < 2; i++) {
                gl16(pA[i] + k0 + TBK, &As[db ^ 1][wave * 32 + i * 16][0]);
                gl16(pB[i] + k0 + TBK, &Bs[db ^ 1][wave * 32 + i * 16][0]);
            }
        }
        __builtin_amdgcn_sched_barrier(0);

        bf16x8 af[4], bfr[4];
        const int kb = lk * 16;
        #pragma unroll
        for (int mi = 0; mi < 4; mi++) {
            const int r = wm * 64 + mi * 16 + l15;
            af[mi] = *(const bf16x8*)((const char*)&As[db][r][0] + (kb ^ (((r >> 1) & 3) << 4)));
        }
        #pragma unroll
        for (int ni = 0; ni < 4; ni++) {
            const int r = wn * 64 + ni * 16 + l15;
            bfr[ni] = *(const bf16x8*)((const char*)&Bs[db][r][0] + (kb ^ (((r >> 1) & 3) << 4)));
        }
        #pragma unroll
        for (int mi = 0; mi < 4; mi++)
            #pragma unroll
            for (int ni = 0; ni < 4; ni++)
                acc[mi][ni] = __builtin_amdgcn_mfma_f32_16x16x32_bf16(
                    af[mi], bfr[ni], acc[mi][ni], 0, 0, 0);

        __syncthreads();   // drains prefetch vmcnt + protects buf reuse
        db ^= 1;
    }

    #pragma unroll
    for (int ni = 0; ni < 4; ni++) {
        const int gc = col0 + wn * 64 + ni * 16 + l15;
        const float bv = bias[gc];
        #pragma unroll
        for (int mi = 0; mi < 4; mi++) {
            #pragma unroll
            for (int r = 0; r < 4; r++) {
                const int gr = row0 + wm * 64 + mi * 16 + lk * 4 + r;
                C[(size_t)gr * Nc + gc] = f2bf(silu_f(acc[mi][ni][r] + bv));
            }
        }
    }
}

// ---------------- gate: logits + top2/flag ----------------

__global__ __launch_bounds__(256) void gate2_topk_flag(
    const unsigned short* __restrict__ g1b, const float* __restrict__ Wg2,
    const float* __restrict__ bg2,
    unsigned* __restrict__ tok_list, float* __restrict__ w_list,
    unsigned* __restrict__ meta, unsigned* __restrict__ flaglist)
{
    const int wid  = threadIdx.x >> 6;
    const int lane = threadIdx.x & 63;
    const int t = blockIdx.x * 4 + wid;
    if (t >= N_TOK) return;

    float acc[NE];
    #pragma unroll
    for (int e = 0; e < NE; e++) acc[e] = 0.0f;

    const unsigned short* g = g1b + (size_t)t * HG;
    for (int kb = lane * 8; kb < HG; kb += 512) {
        ushort4 ga = *(const ushort4*)(g + kb);
        ushort4 gb = *(const ushort4*)(g + kb + 4);
        float gv[8];
        gv[0] = bf2f(ga.x); gv[1] = bf2f(ga.y); gv[2] = bf2f(ga.z); gv[3] = bf2f(ga.w);
        gv[4] = bf2f(gb.x); gv[5] = bf2f(gb.y); gv[6] = bf2f(gb.z); gv[7] = bf2f(gb.w);
        #pragma unroll
        for (int j = 0; j < 8; j++) {
            const float4 wa = *(const float4*)(Wg2 + (size_t)(kb + j) * NE);
            const float4 wb = *(const float4*)(Wg2 + (size_t)(kb + j) * NE + 4);
            acc[0] = fmaf(gv[j], wa.x, acc[0]);
            acc[1] = fmaf(gv[j], wa.y, acc[1]);
            acc[2] = fmaf(gv[j], wa.z, acc[2]);
            acc[3] = fmaf(gv[j], wa.w, acc[3]);
            acc[4] = fmaf(gv[j], wb.x, acc[4]);
            acc[5] = fmaf(gv[j], wb.y, acc[5]);
            acc[6] = fmaf(gv[j], wb.z, acc[6]);
            acc[7] = fmaf(gv[j], wb.w, acc[7]);
        }
    }
    #pragma unroll
    for (int off = 32; off > 0; off >>= 1) {
        #pragma unroll
        for (int e = 0; e < NE; e++)
            acc[e] += __shfl_down(acc[e], off);
    }
    if (lane == 0) {
        float v0 = -3.4e38f, v1 = -3.4e38f, v2 = -3.4e38f;
        int i0 = 0, i1 = 0;
        #pragma unroll
        for (int e = 0; e < NE; e++) {
            const float v = acc[e] + bg2[e];
            if (v > v0)      { v2 = v1; v1 = v0; i1 = i0; v0 = v; i0 = e; }
            else if (v > v1) { v2 = v1; v1 = v; i1 = e; }
            else if (v > v2) { v2 = v; }
        }
        if (v1 - v2 < THETA) {
            const unsigned p = atomicAdd(&meta[17], 1u);
            flaglist[p] = (unsigned)t;
        } else {
            const float e1 = expf(v1 - v0);
            const float inv = 1.0f / (1.0f + e1);
            const unsigned p0 = atomicAdd(&meta[i0], 1u);
            tok_list[i0 * N_TOK + p0] = (unsigned)t;
            w_list [i0 * N_TOK + p0] = inv;
            const unsigned p1 = atomicAdd(&meta[i1], 1u);
            tok_list[i1 * N_TOK + p1] = (unsigned)t;
            w_list [i1 * N_TOK + p1] = e1 * inv;
        }
    }
}

// fp32 gather-GEMM over flagged tokens: g1f[f][2048] = silu(x[flag[f]] @ Wg1 + bg1)
__global__ __launch_bounds__(256) void regate_gemm(
    const float* __restrict__ x, const float* __restrict__ Wg1,
    const float* __restrict__ bg1,
    const unsigned* __restrict__ flaglist, const unsigned* __restrict__ meta,
    float* __restrict__ g1f)
{
    const int nflag = (int)meta[17];
    const int rs = blockIdx.y * BM;
    if (rs >= nflag) return;
    const int re = (rs + BM < nflag) ? rs + BM : nflag;
    const int col0 = blockIdx.x * BN;

    __shared__ float As[BK][BM];
    __shared__ float Bs[BK][BN];

    const int tid = threadIdx.x;
    const int tx = tid & 15;
    const int ty = tid >> 4;
    const int ar = tid >> 2;
    const int ac = (tid & 3) << 2;
    const int br = tid >> 5;
    const int bc = (tid & 31) << 2;

    const int r0 = rs + ar;
    const int r1 = rs + ar + 64;
    const unsigned t0 = flaglist[(r0 < re) ? r0 : rs];
    const unsigned t1 = flaglist[(r1 < re) ? r1 : rs];
    const float* A0 = x + (size_t)t0 * DIM + ac;
    const float* A1 = x + (size_t)t1 * DIM + ac;
    const float* Bp = Wg1 + (size_t)br * HG + col0 + bc;

    float acc[8][8];
    #pragma unroll
    for (int i = 0; i < 8; i++)
        #pragma unroll
        for (int j = 0; j < 8; j++) acc[i][j] = 0.0f;

    for (int k0 = 0; k0 < DIM; k0 += BK) {
        const float4 a0 = *(const float4*)(A0 + k0);
        const float4 a1 = *(const float4*)(A1 + k0);
        const float4 b0 = *(const float4*)(Bp + (size_t)k0 * HG);
        const float4 b1 = *(const float4*)(Bp + (size_t)(k0 + 8) * HG);

        __syncthreads();
        As[ac + 0][ar] = a0.x; As[ac + 1][ar] = a0.y;
        As[ac + 2][ar] = a0.z; As[ac + 3][ar] = a0.w;
        As[ac + 0][ar + 64] = a1.x; As[ac + 1][ar + 64] = a1.y;
        As[ac + 2][ar + 64] = a1.z; As[ac + 3][ar + 64] = a1.w;
        *(float4*)&Bs[br][bc]     = b0;
        *(float4*)&Bs[br + 8][bc] = b1;
        __syncthreads();

        #pragma unroll
        for (int k = 0; k < BK; k++) {
            float a[8], b[8];
            *(float4*)&a[0] = *(const float4*)&As[k][ty * 8];
            *(float4*)&a[4] = *(const float4*)&As[k][ty * 8 + 4];
            *(float4*)&b[0] = *(const float4*)&Bs[k][tx * 8];
            *(float4*)&b[4] = *(const float4*)&Bs[k][tx * 8 + 4];
            #pragma unroll
            for (int i = 0; i < 8; i++)
                #pragma unroll
                for (int j = 0; j < 8; j++)
                    acc[i][j] = fmaf(a[i], b[j], acc[i][j]);
        }
    }

    #pragma unroll
    for (int i = 0; i < 8; i++) {
        const int row = rs + ty * 8 + i;
        if (row < re) {
            const int col = col0 + tx * 8;
            #pragma unroll
            for (int j = 0; j < 8; j++)
                g1f[(size_t)row * HG + col + j] = silu_f(acc[i][j] + bg1[col + j]);
        }
    }
}

// fp32 top2 over recomputed rows; always scatter
__global__ __launch_bounds__(256) void regate_top2(
    const float* __restrict__ g1f, const float* __restrict__ Wg2,
    const float* __restrict__ bg2,
    const unsigned* __restrict__ flaglist,
    unsigned* __restrict__ tok_list, float* __restrict__ w_list,
    unsigned* __restrict__ meta)
{
    const int wid  = threadIdx.x >> 6;
    const int lane = threadIdx.x & 63;
    const int f = blockIdx.x * 4 + wid;
    const int nflag = (int)meta[17];
    if (f >= nflag) return;
    const unsigned t = flaglist[f];

    float acc[NE];
    #pragma unroll
    for (int e = 0; e < NE; e++) acc[e] = 0.0f;

    const float* g = g1f + (size_t)f * HG;
    for (int k = lane; k < HG; k += 64) {
        const float gv = g[k];
        const float4 wa = *(const float4*)(Wg2 + (size_t)k * NE);
        const float4 wb = *(const float4*)(Wg2 + (size_t)k * NE + 4);
        acc[0] = fmaf(gv, wa.x, acc[0]);
        acc[1] = fmaf(gv, wa.y, acc[1]);
        acc[2] = fmaf(gv, wa.z, acc[2]);
        acc[3] = fmaf(gv, wa.w, acc[3]);
        acc[4] = fmaf(gv, wb.x, acc[4]);
        acc[5] = fmaf(gv, wb.y, acc[5]);
        acc[6] = fmaf(gv, wb.z, acc[6]);
        acc[7] = fmaf(gv, wb.w, acc[7]);
    }
    #pragma unroll
    for (int off = 32; off > 0; off >>= 1) {
        #pragma unroll
        for (int e = 0; e < NE; e++)
            acc[e] += __shfl_down(acc[e], off);
    }
    if (lane == 0) {
        float v0 = -3.4e38f, v1 = -3.4e38f;
        int i0 = 0, i1 = 0;
        #pragma unroll
        for (int e = 0; e < NE; e++) {
            const float v = acc[e] + bg2[e];
            if (v > v0) { v1 = v0; i1 = i0; v0 = v; i0 = e; }
            else if (v > v1) { v1 = v; i1 = e; }
        }
        const float e1 = expf(v1 - v0);
        const float inv = 1.0f / (1.0f + e1);
        const unsigned p0 = atomicAdd(&meta[i0], 1u);
        tok_list[i0 * N_TOK + p0] = (unsigned)t;
        w_list [i0 * N_TOK + p0] = inv;
        const unsigned p1 = atomicAdd(&meta[i1], 1u);
        tok_list[i1 * N_TOK + p1] = (unsigned)t;
        w_list [i1 * N_TOK + p1] = e1 * inv;
    }
}

// meta[0..7] = counts (in), meta[16] = n_tiles (out)
__global__ void build_tiles(unsigned* __restrict__ meta,
                            unsigned* __restrict__ tile_e,
                            unsigned* __restrict__ tile_rs,
                            unsigned* __restrict__ tile_re)
{
    if (threadIdx.x == 0 && blockIdx.x == 0) {
        int nt = 0;
        for (int e = 0; e < NE; e++) {
            const unsigned c = meta[e];
            for (unsigned s = 0; s < c; s += 128) {
                tile_e[nt]  = (unsigned)e;
                tile_rs[nt] = (unsigned)(e * N_TOK) + s;
                unsigned re = s + 128; if (re > c) re = c;
                tile_re[nt] = (unsigned)(e * N_TOK) + re;
                nt++;
            }
        }
        meta[16] = (unsigned)nt;
    }
}

// grouped ff2: out[tok] += w * (h[tok] @ W2t[e]^T + b2[e]); W2t is [e][1024][4096] (N,K)
// grid: x = col block (8, fastest -> A-tile reuse in L2/L3), y = token tile
__global__ __launch_bounds__(256) void ff2_mfma(
    const unsigned short* __restrict__ Hb,
    const unsigned short* __restrict__ W2t,
    const float* __restrict__ b2,
    const unsigned* __restrict__ tok_list, const float* __restrict__ w_list,
    const unsigned* __restrict__ meta,
    const unsigned* __restrict__ tile_e, const unsigned* __restrict__ tile_rs,
    const unsigned* __restrict__ tile_re,
    float* __restrict__ out)
{
    const unsigned nt = meta[16];
    if (blockIdx.y >= nt) return;

    const int e  = (int)tile_e[blockIdx.y];
    const int rs = (int)tile_rs[blockIdx.y];
    const int re = (int)tile_re[blockIdx.y];
    const int col0 = blockIdx.x * 128;

    __shared__ __align__(16) unsigned short As[2][128][TBK];
    __shared__ __align__(16) unsigned short Bs[2][128][TBK];
    __shared__ unsigned tokr[128];

    const int tid  = threadIdx.x;
    const int wave = tid >> 6;
    const int lane = tid & 63;
    const int wm = wave >> 1, wn = wave & 1;
    const int l15 = lane & 15;
    const int lk  = lane >> 4;

    if (tid < 128)
        tokr[tid] = (rs + tid < re) ? tok_list[rs + tid] : tok_list[rs];
    __syncthreads();

    const unsigned short* Bsrc = W2t + (size_t)e * DIM * HEXP;

    const int srow = lane >> 2;
    const int cbs  = (lane & 3) ^ ((lane >> 3) & 3);
    const unsigned short* pA[2];
    const unsigned short* pB[2];
    #pragma unroll
    for (int i = 0; i < 2; i++) {
        const int r = wave * 32 + i * 16 + srow;
        pA[i] = Hb + (size_t)tokr[r] * HEXP + cbs * 8;
        pB[i] = Bsrc + (size_t)(col0 + r) * HEXP + cbs * 8;
    }

    f32x4 acc[4][4] = {};

    #pragma unroll
    for (int i = 0; i < 2; i++) {
        gl16(pA[i], &As[0][wave * 32 + i * 16][0]);
        gl16(pB[i], &Bs[0][wave * 32 + i * 16][0]);
    }
    __syncthreads();

    int db = 0;
    for (int k0 = 0; k0 < HEXP; k0 += TBK) {
        if (k0 + TBK < HEXP) {
            #pragma unroll
            for (int i = 0; i < 2; i++) {
                gl16(pA[i] + k0 + TBK, &As[db ^ 1][wave * 32 + i * 16][0]);
                gl16(pB[i] + k0 + TBK, &Bs[db ^ 1][wave * 32 + i * 16][0]);
            }
        }
        __builtin_amdgcn_sched_barrier(0);

        bf16x8 af[4], bfr[4];
        const int kb = lk * 16;
        #pragma unroll
        for (int mi = 0; mi < 4; mi++) {
            const int r = wm * 64 + mi * 16 + l15;
            af[mi] = *(const bf16x8*)((const char*)&As[db][r][0] + (kb ^ (((r >> 1) & 3) << 4)));
        }
        #pragma unroll
        for (int ni = 0; ni < 4; ni++) {
            const int r = wn * 64 + ni * 16 + l15;
            bfr[ni] = *(const bf16x8*)((const char*)&Bs[db][r][0] + (kb ^ (((r >> 1) & 3) << 4)));
        }
        #pragma unroll
        for (int mi = 0; mi < 4; mi++)
            #pragma unroll
            for (int ni = 0; ni < 4; ni++)
                acc[mi][ni] = __builtin_amdgcn_mfma_f32_16x16x32_bf16(
                    af[mi], bfr[ni], acc[mi][ni], 0, 0, 0);

        __syncthreads();
        db ^= 1;
    }

    #pragma unroll
    for (int ni = 0; ni < 4; ni++) {
        const int gc = col0 + wn * 64 + ni * 16 + l15;
        const float bv = b2[(size_t)e * DIM + gc];
        #pragma unroll
        for (int mi = 0; mi < 4; mi++) {
            #pragma unroll
            for (int r = 0; r < 4; r++) {
                const int lr = wm * 64 + mi * 16 + lk * 4 + r;
                if (rs + lr < re) {
                    const unsigned tok = tokr[lr];
                    const float w = w_list[rs + lr];
                    atomicAdd(out + (size_t)tok * DIM + gc, w * (acc[mi][ni][r] + bv));
                }
            }
        }
    }
}

extern "C" void kernel_launch(void* const* d_in, const int* in_sizes, int n_in,
                              void* d_out, int out_size, void* d_ws, size_t ws_size,
                              hipStream_t stream)
{
    const float* x   = (const float*)d_in[0];
    const float* Wg1 = (const float*)d_in[1];
    const float* bg1 = (const float*)d_in[2];
    const float* Wg2 = (const float*)d_in[3];
    const float* bg2 = (const float*)d_in[4];
    const float* W1  = (const float*)d_in[5];
    const float* b1  = (const float*)d_in[6];
    const float* W2  = (const float*)d_in[7];
    const float* b2  = (const float*)d_in[8];
    float* out = (float*)d_out;

    char* ws = (char*)d_ws;
    const size_t MB = 1024 * 1024;
    // layout (region 28..92MB time-shared: g1b -> g1f -> hbuf)
    unsigned short* xb   = (unsigned short*)(ws);             // 16MB [8192][1024] bf16
    unsigned short* W1t  = (unsigned short*)(ws + 16 * MB);   //  8MB [4096][1024] bf16
    unsigned short* Wg1t = (unsigned short*)(ws + 24 * MB);   //  4MB [2048][1024] bf16
    unsigned short* g1b  = (unsigned short*)(ws + 28 * MB);   // 32MB [8192][2048] bf16
    float*          g1f  = (float*)        (ws + 28 * MB);    // 64MB [nflag][2048] f32
    unsigned short* hbuf = (unsigned short*)(ws + 28 * MB);   // 64MB [8192][4096] bf16
    unsigned short* W2t  = (unsigned short*)(ws + 92 * MB);   // 64MB [8][1024][4096] bf16
    unsigned* tok_list = (unsigned*)(ws + 156 * MB);          // [8][8192] u32
    float*    w_list   = (float*)   (ws + 156 * MB + 65536 * 4);
    unsigned* meta     = (unsigned*)(ws + 156 * MB + 65536 * 8); // [0..7]=counts,[16]=ntiles,[17]=nflag
    unsigned* tile_e   = meta + 1024;
    unsigned* tile_rs  = meta + 1280;
    unsigned* tile_re  = meta + 1536;
    unsigned* flaglist = meta + 2048;                            // [8192] u32

    (void)hipMemsetAsync(d_out, 0, (size_t)out_size * sizeof(float), stream);
    (void)hipMemsetAsync(meta, 0, 128, stream);

    const dim3 blk(256);
    // prep
    conv_x<<<dim3(2048), blk, 0, stream>>>(x, xb);
    transpose_conv<<<dim3(HG / 64, DIM / 64, 1), blk, 0, stream>>>(Wg1, Wg1t, DIM, HG);
    // gate1 (bf16 MFMA): g1b = silu(x @ Wg1 + bg1)
    gemm_bf16_silu<<<dim3(HG / 128, N_TOK / 128), blk, 0, stream>>>(xb, Wg1t, bg1, g1b, HG);
    // logits + top2 with margin flagging
    gate2_topk_flag<<<dim3(N_TOK / 4), blk, 0, stream>>>(
        g1b, Wg2, bg2, tok_list, w_list, meta, flaglist);
    // fp32 recompute of flagged tokens (g1b dead; g1f overlays it)
    regate_gemm<<<dim3(HG / BN, N_TOK / BM), blk, 0, stream>>>(
        x, Wg1, bg1, flaglist, meta, g1f);
    regate_top2<<<dim3(N_TOK / 4), blk, 0, stream>>>(
        g1f, Wg2, bg2, flaglist, tok_list, w_list, meta);
    // tile table
    build_tiles<<<dim3(1), dim3(64), 0, stream>>>(meta, tile_e, tile_rs, tile_re);
    // ff1 (bf16 MFMA): hbuf = silu(x @ W1 + b1)  (overwrites dead g1f)
    transpose_conv<<<dim3(HEXP / 64, DIM / 64, 1), blk, 0, stream>>>(W1, W1t, DIM, HEXP);
    gemm_bf16_silu<<<dim3(HEXP / 128, N_TOK / 128), blk, 0, stream>>>(xb, W1t, b1, hbuf, HEXP);
    // W2 -> W2t bf16
    transpose_conv<<<dim3(DIM / 64, HEXP / 64, NE), blk, 0, stream>>>(W2, W2t, HEXP, DIM);
    // grouped ff2 (col-fastest grid for A-tile L2/L3 reuse)
    ff2_mfma<<<dim3(DIM / 128, N_TOK * 2 / 128 + NE), blk, 0, stream>>>(
        hbuf, W2t, b2, tok_list, w_list, meta, tile_e, tile_rs, tile_re, out);
}